// Round 28
// baseline (200.900 us; speedup 1.0000x reference)
//
#include <hip/hip_runtime.h>

#pragma clang fp contract(off)

#define NB 16
#define NV 100000
#define NF 200000
#define NP 65536

// XLA ReduceWindowRewriter, base_length = 16:
// 200000 = 12500*16, then 12500 -> 782 -> 49 -> 4 (sequential windows).
#define B16 16
#define NW0 12500
#define NW1 782
#define NW2 49
#define NW3 4

#define TREE_LVL 12              // top levels of the search served from LDS
#define TREE_N   (1 << TREE_LVL) // 4096 slots (index 0 unused)

// XCD-aware swizzle: batches {2x,2x+1} pin to XCD x (blockIdx%8 round-robin).
__device__ __forceinline__ void xcd_map(int p, int& batch, int& chunk) {
    int r = p & 15;
    batch = 2 * (r & 7) + (r >> 3);
    chunk = p >> 4;
}

// ---------------------------------------------------------------------------
__global__ void detect_kernel(const int* __restrict__ faces, int* __restrict__ flag) {
    __shared__ int any;
    if (threadIdx.x == 0) any = 0;
    __syncthreads();
    int acc = 0;
    for (int i = threadIdx.x; i < 4096; i += blockDim.x)
        acc |= faces[2 * i + 1];
    if (acc) atomicOr(&any, 1);
    __syncthreads();
    if (threadIdx.x == 0) flag[0] = (any == 0) ? 1 : 0;
}

__device__ __forceinline__ void load_face(const int* __restrict__ faces,
                                          long long fidx, int is64,
                                          int& i0, int& i1, int& i2) {
    if (is64) {
        const int* p = faces + fidx * 6;
        i0 = p[0]; i1 = p[2]; i2 = p[4];
    } else {
        const int* p = faces + fidx * 3;
        i0 = p[0]; i1 = p[1]; i2 = p[2];
    }
}

// ---------------------------------------------------------------------------
// FUSED area + window-16 prefix (bit-exact to split version):
// each thread computes its FMA-contracted area into LDS, then re-sums its
// window prefix in the identical sequential order. Chunk = 256 faces = 16
// aligned windows (NF % 16 == 0, chunk % 16 == 0).
// ---------------------------------------------------------------------------
__global__ void area_prefix_kernel(const float* __restrict__ verts,
                                   const int* __restrict__ faces,
                                   const int* __restrict__ flag,
                                   float* __restrict__ cdf,
                                   float* __restrict__ s0) {
    __shared__ float S[256];
    int batch, chunk;
    xcd_map(blockIdx.x, batch, chunk);
    int tid = threadIdx.x;
    int i = chunk * 256 + tid;
    bool valid = (i < NF);
    float a = 0.0f;
    if (valid) {
        int is64 = flag[0];
        size_t gid = (size_t)batch * NF + i;
        const float* vb = verts + (size_t)batch * NV * 3;
        int i0, i1, i2;
        load_face(faces, (long long)gid, is64, i0, i1, i2);
        float ax = vb[3 * i0 + 0], ay = vb[3 * i0 + 1], az = vb[3 * i0 + 2];
        float bx = vb[3 * i1 + 0], by = vb[3 * i1 + 1], bz = vb[3 * i1 + 2];
        float cx = vb[3 * i2 + 0], cy = vb[3 * i2 + 1], cz = vb[3 * i2 + 2];
        float v1x = bx - ax, v1y = by - ay, v1z = bz - az;
        float v2x = cx - ax, v2y = cy - ay, v2z = cz - az;
        float nx = fmaf(v1y, v2z, -(v1z * v2y));
        float ny = fmaf(v1z, v2x, -(v1x * v2z));
        float nz = fmaf(v1x, v2y, -(v1y * v2x));
        float ss = fmaf(nz, nz, fmaf(nx, nx, ny * ny));
        float nrm = sqrtf(ss);
        a = nrm / 2.0f;
    }
    S[tid] = a;
    __syncthreads();
    if (valid) {
        int base = tid & ~15;
        float run = S[base];
        for (int p = base + 1; p <= tid; ++p) run = run + S[p];  // seq order
        cdf[(size_t)batch * NF + i] = run;
        if ((tid & 15) == 15)
            s0[(size_t)batch * NW0 + (i >> 4)] = run;
    }
}

// ---------------------------------------------------------------------------
// Stage B: per batch, scan s0[12500] with the SAME base-16 structure.
// ---------------------------------------------------------------------------
__global__ void midscan16_kernel(const float* __restrict__ s0g, float* __restrict__ S0g) {
    __shared__ float t0[NW0];
    __shared__ float t1[NW1];
    __shared__ float t2[NW2];
    __shared__ float t3[NW3];
    int b = blockIdx.x;
    for (int i = threadIdx.x; i < NW0; i += blockDim.x)
        t0[i] = s0g[(size_t)b * NW0 + i];
    __syncthreads();
    for (int w = threadIdx.x; w < NW1; w += blockDim.x) {
        int st = w * B16, en = st + B16 < NW0 ? st + B16 : NW0;
        float run = 0.0f;
        for (int p = st; p < en; ++p) { run = run + t0[p]; t0[p] = run; }
        t1[w] = run;
    }
    __syncthreads();
    for (int w = threadIdx.x; w < NW2; w += blockDim.x) {
        int st = w * B16, en = st + B16 < NW1 ? st + B16 : NW1;
        float run = 0.0f;
        for (int p = st; p < en; ++p) { run = run + t1[p]; t1[p] = run; }
        t2[w] = run;
    }
    __syncthreads();
    for (int w = threadIdx.x; w < NW3; w += blockDim.x) {
        int st = w * B16, en = st + B16 < NW2 ? st + B16 : NW2;
        float run = 0.0f;
        for (int p = st; p < en; ++p) { run = run + t2[p]; t2[p] = run; }
        t3[w] = run;
    }
    __syncthreads();
    if (threadIdx.x == 0) {
        float run = 0.0f;
        for (int k = 0; k < NW3; ++k) { run = run + t3[k]; t3[k] = run; }
    }
    __syncthreads();
    for (int i = threadIdx.x; i < NW2; i += blockDim.x) {
        int w = i >> 4;
        float off = (w > 0) ? t3[w - 1] : 0.0f;
        t2[i] = off + t2[i];
    }
    __syncthreads();
    for (int i = threadIdx.x; i < NW1; i += blockDim.x) {
        int w = i >> 4;
        float off = (w > 0) ? t2[w - 1] : 0.0f;
        t1[i] = off + t1[i];
    }
    __syncthreads();
    for (int i = threadIdx.x; i < NW0; i += blockDim.x) {
        int w = i >> 4;
        float off = (w > 0) ? t1[w - 1] : 0.0f;
        t0[i] = off + t0[i];
    }
    __syncthreads();
    for (int i = threadIdx.x; i < NW0; i += blockDim.x)
        S0g[(size_t)b * NW0 + i] = t0[i];
}

// ---------------------------------------------------------------------------
// FUSED addoff + normalize (bit-exact): total = S0[NW0-2] + s0[NW0-1];
// rcp = 1/total; cdf[i] = (off + cdf[i]) * rcp.
// ---------------------------------------------------------------------------
__global__ void fused_norm_kernel(float* __restrict__ cdf,
                                  const float* __restrict__ s0,
                                  const float* __restrict__ S0) {
    int batch, chunk;
    xcd_map(blockIdx.x, batch, chunk);
    int i = chunk * 256 + threadIdx.x;
    if (i >= NF) return;
    const float* S0b = S0 + (size_t)batch * NW0;
    float total = S0b[NW0 - 2] + s0[(size_t)batch * NW0 + NW0 - 1];
    float rcp = 1.0f / total;
    int j = i >> 4;
    float off = (j > 0) ? S0b[j - 1] : 0.0f;
    float* p = cdf + (size_t)batch * NF + i;
    *p = (off + *p) * rcp;
}

// ---------------------------------------------------------------------------
// Sample: searchsorted 'scan' (18 levels) with the TOP 12 LEVELS served from
// an LDS tree. Node n at level k has a FIXED (low,high) obtained by replaying
// n's path bits; T[n] = c[midpoint]. Comparisons are identical to the global
// version -> bit-exact. Remaining 6 levels read global. f64 epilogue.
// ---------------------------------------------------------------------------
__global__ void sample_kernel(const float* __restrict__ verts,
                              const int* __restrict__ faces,
                              const int* __restrict__ flag,
                              const float* __restrict__ e1,
                              const float* __restrict__ e2,
                              const float* __restrict__ u,
                              const float* __restrict__ cdf,
                              float* __restrict__ out) {
    __shared__ float T[TREE_N];
    int batch, chunk;
    xcd_map(blockIdx.x, batch, chunk);
    int b = batch;
    const float* c = cdf + (size_t)b * NF;

    // Build the top tree: node n (1..4095), level k = 31-clz(n), path bits
    // = bits k-1..0 of n (MSB-first), replay to get this node's interval.
    for (int n = 1 + threadIdx.x; n < TREE_N; n += blockDim.x) {
        int k = 31 - __clz(n);
        int low = 0, high = NF;
        for (int j = k - 1; j >= 0; --j) {
            int mid = (low + high) >> 1;
            if ((n >> j) & 1) low = mid; else high = mid;
        }
        T[n] = c[(low + high) >> 1];
    }
    __syncthreads();

    int li = chunk * 256 + threadIdx.x;      // sample index in [0, NP)
    int gid = (b << 16) + li;                // P = 65536
    int is64 = flag[0];

    float uv = u[gid];
    int low = 0, high = NF, node = 1;
    #pragma unroll
    for (int it = 0; it < TREE_LVL; ++it) {  // LDS levels
        int mid = (low + high) >> 1;
        bool gl = (uv <= T[node]);
        node = 2 * node + (gl ? 0 : 1);
        if (gl) high = mid; else low = mid;
    }
    #pragma unroll
    for (int it = TREE_LVL; it < 18; ++it) { // global levels
        int mid = (low + high) >> 1;
        bool gl = (uv <= c[mid]);
        if (gl) high = mid; else low = mid;
    }
    int idx = high < NF - 1 ? high : NF - 1;

    const float* vb = verts + (size_t)b * NV * 3;
    int i0, i1, i2;
    load_face(faces, (long long)b * NF + idx, is64, i0, i1, i2);
    double ax = vb[3 * i0 + 0], ay = vb[3 * i0 + 1], az = vb[3 * i0 + 2];
    double bx = vb[3 * i1 + 0], by = vb[3 * i1 + 1], bz = vb[3 * i1 + 2];
    double cx = vb[3 * i2 + 0], cy = vb[3 * i2 + 1], cz = vb[3 * i2 + 2];

    double v1x = bx - ax, v1y = by - ay, v1z = bz - az;
    double v2x = cx - ax, v2y = cy - ay, v2z = cz - az;
    double nx = v1y * v2z - v1z * v2y;
    double ny = v1z * v2x - v1x * v2z;
    double nz = v1x * v2y - v1y * v2x;
    double ss = (nx * nx + ny * ny) + nz * nz;
    double nrm = sqrt(ss);
    double unx = nx / nrm, uny = ny / nrm, unz = nz / nrm;

    double s = sqrt((double)e1[gid]);
    double t = (double)e2[gid];
    double w0 = 1.0 - s;
    double w1 = (1.0 - t) * s;
    double w2 = t * s;
    double px = (ax * w0 + bx * w1) + cx * w2;
    double py = (ay * w0 + by * w1) + cy * w2;
    double pz = (az * w0 + bz * w1) + cz * w2;

    size_t po = (size_t)gid * 3;
    out[po + 0] = (float)px;
    out[po + 1] = (float)py;
    out[po + 2] = (float)pz;
    size_t no = (size_t)NB * NP * 3 + po;
    out[no + 0] = (float)unx;
    out[no + 1] = (float)uny;
    out[no + 2] = (float)unz;
}

extern "C" void kernel_launch(void* const* d_in, const int* in_sizes, int n_in,
                              void* d_out, int out_size, void* d_ws, size_t ws_size,
                              hipStream_t stream) {
    const float* verts = (const float*)d_in[0];  // fp32
    const int*   faces = (const int*)d_in[1];    // int32 (guarded for int64)
    const float* e1    = (const float*)d_in[2];
    const float* e2    = (const float*)d_in[3];
    const float* u     = (const float*)d_in[4];
    float* out = (float*)d_out;

    char* ws = (char*)d_ws;
    int*   flag = (int*)ws;                                  // 256 B
    float* cdf  = (float*)(ws + 512);                        // 12.8 MB
    float* s0   = (float*)(ws + 512 + (size_t)NB * NF * 4);               // 800 KB
    float* S0   = (float*)(ws + 512 + (size_t)NB * NF * 4 + (size_t)NB * NW0 * 4);

    detect_kernel<<<1, 256, 0, stream>>>(faces, flag);

    // fused area + window-prefix: 16 batches x 782 chunks (XCD-swizzled)
    area_prefix_kernel<<<16 * 782, 256, 0, stream>>>(verts, faces, flag, cdf, s0);

    midscan16_kernel<<<NB, 256, 0, stream>>>(s0, S0);

    // fused addoff + normalize: 16 batches x 782 chunks (XCD-swizzled)
    fused_norm_kernel<<<16 * 782, 256, 0, stream>>>(cdf, s0, S0);

    // sample with LDS top-tree: 16 batches x 256 chunks (XCD-swizzled)
    sample_kernel<<<16 * 256, 256, 0, stream>>>(verts, faces, flag, e1, e2, u, cdf, out);
}

// Round 29
// 169.205 us; speedup vs baseline: 1.1873x; 1.1873x over previous
//
#include <hip/hip_runtime.h>

#pragma clang fp contract(off)

#define NB 16
#define NV 100000
#define NF 200000
#define NP 65536

// XLA ReduceWindowRewriter, base_length = 16:
// 200000 = 12500*16, then 12500 -> 782 -> 49 -> 4 (sequential windows).
#define B16 16
#define NW0 12500
#define NW1 782
#define NW2 49
#define NW3 4

// XCD-aware swizzle: batches {2x,2x+1} pin to XCD x (blockIdx%8 round-robin).
__device__ __forceinline__ void xcd_map(int p, int& batch, int& chunk) {
    int r = p & 15;
    batch = 2 * (r & 7) + (r >> 3);
    chunk = p >> 4;
}

// ---------------------------------------------------------------------------
__global__ void detect_kernel(const int* __restrict__ faces, int* __restrict__ flag) {
    __shared__ int any;
    if (threadIdx.x == 0) any = 0;
    __syncthreads();
    int acc = 0;
    for (int i = threadIdx.x; i < 4096; i += blockDim.x)
        acc |= faces[2 * i + 1];
    if (acc) atomicOr(&any, 1);
    __syncthreads();
    if (threadIdx.x == 0) flag[0] = (any == 0) ? 1 : 0;
}

__device__ __forceinline__ void load_face(const int* __restrict__ faces,
                                          long long fidx, int is64,
                                          int& i0, int& i1, int& i2) {
    if (is64) {
        const int* p = faces + fidx * 6;
        i0 = p[0]; i1 = p[2]; i2 = p[4];
    } else {
        const int* p = faces + fidx * 3;
        i0 = p[0]; i1 = p[1]; i2 = p[2];
    }
}

// ---------------------------------------------------------------------------
// FUSED area + window-16 prefix (bit-exact, kept from R28 — it helped):
// FMA-contracted area into LDS, then re-sum window prefix in the identical
// sequential order. Chunk = 256 faces = 16 aligned windows.
// ---------------------------------------------------------------------------
__global__ void area_prefix_kernel(const float* __restrict__ verts,
                                   const int* __restrict__ faces,
                                   const int* __restrict__ flag,
                                   float* __restrict__ cdf,
                                   float* __restrict__ s0) {
    __shared__ float S[256];
    int batch, chunk;
    xcd_map(blockIdx.x, batch, chunk);
    int tid = threadIdx.x;
    int i = chunk * 256 + tid;
    bool valid = (i < NF);
    float a = 0.0f;
    if (valid) {
        int is64 = flag[0];
        size_t gid = (size_t)batch * NF + i;
        const float* vb = verts + (size_t)batch * NV * 3;
        int i0, i1, i2;
        load_face(faces, (long long)gid, is64, i0, i1, i2);
        float ax = vb[3 * i0 + 0], ay = vb[3 * i0 + 1], az = vb[3 * i0 + 2];
        float bx = vb[3 * i1 + 0], by = vb[3 * i1 + 1], bz = vb[3 * i1 + 2];
        float cx = vb[3 * i2 + 0], cy = vb[3 * i2 + 1], cz = vb[3 * i2 + 2];
        float v1x = bx - ax, v1y = by - ay, v1z = bz - az;
        float v2x = cx - ax, v2y = cy - ay, v2z = cz - az;
        float nx = fmaf(v1y, v2z, -(v1z * v2y));
        float ny = fmaf(v1z, v2x, -(v1x * v2z));
        float nz = fmaf(v1x, v2y, -(v1y * v2x));
        float ss = fmaf(nz, nz, fmaf(nx, nx, ny * ny));
        float nrm = sqrtf(ss);
        a = nrm / 2.0f;
    }
    S[tid] = a;
    __syncthreads();
    if (valid) {
        int base = tid & ~15;
        float run = S[base];
        for (int p = base + 1; p <= tid; ++p) run = run + S[p];  // seq order
        cdf[(size_t)batch * NF + i] = run;
        if ((tid & 15) == 15)
            s0[(size_t)batch * NW0 + (i >> 4)] = run;
    }
}

// ---------------------------------------------------------------------------
// Stage B: per batch, scan s0[12500] with the SAME base-16 structure.
// ---------------------------------------------------------------------------
__global__ void midscan16_kernel(const float* __restrict__ s0g, float* __restrict__ S0g) {
    __shared__ float t0[NW0];
    __shared__ float t1[NW1];
    __shared__ float t2[NW2];
    __shared__ float t3[NW3];
    int b = blockIdx.x;
    for (int i = threadIdx.x; i < NW0; i += blockDim.x)
        t0[i] = s0g[(size_t)b * NW0 + i];
    __syncthreads();
    for (int w = threadIdx.x; w < NW1; w += blockDim.x) {
        int st = w * B16, en = st + B16 < NW0 ? st + B16 : NW0;
        float run = 0.0f;
        for (int p = st; p < en; ++p) { run = run + t0[p]; t0[p] = run; }
        t1[w] = run;
    }
    __syncthreads();
    for (int w = threadIdx.x; w < NW2; w += blockDim.x) {
        int st = w * B16, en = st + B16 < NW1 ? st + B16 : NW1;
        float run = 0.0f;
        for (int p = st; p < en; ++p) { run = run + t1[p]; t1[p] = run; }
        t2[w] = run;
    }
    __syncthreads();
    for (int w = threadIdx.x; w < NW3; w += blockDim.x) {
        int st = w * B16, en = st + B16 < NW2 ? st + B16 : NW2;
        float run = 0.0f;
        for (int p = st; p < en; ++p) { run = run + t2[p]; t2[p] = run; }
        t3[w] = run;
    }
    __syncthreads();
    if (threadIdx.x == 0) {
        float run = 0.0f;
        for (int k = 0; k < NW3; ++k) { run = run + t3[k]; t3[k] = run; }
    }
    __syncthreads();
    for (int i = threadIdx.x; i < NW2; i += blockDim.x) {
        int w = i >> 4;
        float off = (w > 0) ? t3[w - 1] : 0.0f;
        t2[i] = off + t2[i];
    }
    __syncthreads();
    for (int i = threadIdx.x; i < NW1; i += blockDim.x) {
        int w = i >> 4;
        float off = (w > 0) ? t2[w - 1] : 0.0f;
        t1[i] = off + t1[i];
    }
    __syncthreads();
    for (int i = threadIdx.x; i < NW0; i += blockDim.x) {
        int w = i >> 4;
        float off = (w > 0) ? t1[w - 1] : 0.0f;
        t0[i] = off + t0[i];
    }
    __syncthreads();
    for (int i = threadIdx.x; i < NW0; i += blockDim.x)
        S0g[(size_t)b * NW0 + i] = t0[i];
}

// ---------------------------------------------------------------------------
// FUSED addoff + normalize (bit-exact): total = S0[NW0-2] + s0[NW0-1];
// rcp = 1/total; cdf[i] = (off + cdf[i]) * rcp.
// ---------------------------------------------------------------------------
__global__ void fused_norm_kernel(float* __restrict__ cdf,
                                  const float* __restrict__ s0,
                                  const float* __restrict__ S0) {
    int batch, chunk;
    xcd_map(blockIdx.x, batch, chunk);
    int i = chunk * 256 + threadIdx.x;
    if (i >= NF) return;
    const float* S0b = S0 + (size_t)batch * NW0;
    float total = S0b[NW0 - 2] + s0[(size_t)batch * NW0 + NW0 - 1];
    float rcp = 1.0f / total;
    int j = i >> 4;
    float off = (j > 0) ? S0b[j - 1] : 0.0f;
    float* p = cdf + (size_t)batch * NF + i;
    *p = (off + *p) * rcp;
}

// ---------------------------------------------------------------------------
// Epilogue for one sample (f64, stored f32).
// ---------------------------------------------------------------------------
__device__ __forceinline__ void epilogue(const float* __restrict__ vb,
                                         const int* __restrict__ faces,
                                         long long fidx, int is64,
                                         const float* __restrict__ e1,
                                         const float* __restrict__ e2,
                                         int gid, float* __restrict__ out) {
    int i0, i1, i2;
    load_face(faces, fidx, is64, i0, i1, i2);
    double ax = vb[3 * i0 + 0], ay = vb[3 * i0 + 1], az = vb[3 * i0 + 2];
    double bx = vb[3 * i1 + 0], by = vb[3 * i1 + 1], bz = vb[3 * i1 + 2];
    double cx = vb[3 * i2 + 0], cy = vb[3 * i2 + 1], cz = vb[3 * i2 + 2];

    double v1x = bx - ax, v1y = by - ay, v1z = bz - az;
    double v2x = cx - ax, v2y = cy - ay, v2z = cz - az;
    double nx = v1y * v2z - v1z * v2y;
    double ny = v1z * v2x - v1x * v2z;
    double nz = v1x * v2y - v1y * v2x;
    double ss = (nx * nx + ny * ny) + nz * nz;
    double nrm = sqrt(ss);
    double unx = nx / nrm, uny = ny / nrm, unz = nz / nrm;

    double s = sqrt((double)e1[gid]);
    double t = (double)e2[gid];
    double w0 = 1.0 - s;
    double w1 = (1.0 - t) * s;
    double w2 = t * s;
    double px = (ax * w0 + bx * w1) + cx * w2;
    double py = (ay * w0 + by * w1) + cy * w2;
    double pz = (az * w0 + bz * w1) + cz * w2;

    size_t po = (size_t)gid * 3;
    out[po + 0] = (float)px;
    out[po + 1] = (float)py;
    out[po + 2] = (float)pz;
    size_t no = (size_t)NB * NP * 3 + po;
    out[no + 0] = (float)unx;
    out[no + 1] = (float)uny;
    out[no + 2] = (float)unz;
}

// ---------------------------------------------------------------------------
// Sample: 2 samples/thread with INTERLEAVED search chains (2x memory-level
// parallelism on the 18-level dependent-load chain). Comparisons per sample
// identical to R27 -> bit-exact. Grid: 16 batches x 128 chunks of 512 samples.
// ---------------------------------------------------------------------------
__global__ void sample_kernel(const float* __restrict__ verts,
                              const int* __restrict__ faces,
                              const int* __restrict__ flag,
                              const float* __restrict__ e1,
                              const float* __restrict__ e2,
                              const float* __restrict__ u,
                              const float* __restrict__ cdf,
                              float* __restrict__ out) {
    int batch, chunk;
    xcd_map(blockIdx.x, batch, chunk);
    int b = batch;
    const float* c = cdf + (size_t)b * NF;
    int is64 = flag[0];

    int li0 = chunk * 512 + threadIdx.x;     // sample A
    int li1 = li0 + 256;                     // sample B (coalesced pairing)
    int g0 = (b << 16) + li0;
    int g1 = (b << 16) + li1;

    float uv0 = u[g0], uv1 = u[g1];
    int lo0 = 0, hi0 = NF, lo1 = 0, hi1 = NF;
    #pragma unroll
    for (int it = 0; it < 18; ++it) {        // ceil(log2(200001)) = 18
        int m0 = (lo0 + hi0) >> 1;
        int m1 = (lo1 + hi1) >> 1;
        float c0 = c[m0];                    // both loads issue before use
        float c1 = c[m1];
        bool gl0 = (uv0 <= c0);
        bool gl1 = (uv1 <= c1);
        lo0 = gl0 ? lo0 : m0;  hi0 = gl0 ? m0 : hi0;
        lo1 = gl1 ? lo1 : m1;  hi1 = gl1 ? m1 : hi1;
    }
    int idx0 = hi0 < NF - 1 ? hi0 : NF - 1;
    int idx1 = hi1 < NF - 1 ? hi1 : NF - 1;

    const float* vb = verts + (size_t)b * NV * 3;
    epilogue(vb, faces, (long long)b * NF + idx0, is64, e1, e2, g0, out);
    epilogue(vb, faces, (long long)b * NF + idx1, is64, e1, e2, g1, out);
}

extern "C" void kernel_launch(void* const* d_in, const int* in_sizes, int n_in,
                              void* d_out, int out_size, void* d_ws, size_t ws_size,
                              hipStream_t stream) {
    const float* verts = (const float*)d_in[0];  // fp32
    const int*   faces = (const int*)d_in[1];    // int32 (guarded for int64)
    const float* e1    = (const float*)d_in[2];
    const float* e2    = (const float*)d_in[3];
    const float* u     = (const float*)d_in[4];
    float* out = (float*)d_out;

    char* ws = (char*)d_ws;
    int*   flag = (int*)ws;                                  // 256 B
    float* cdf  = (float*)(ws + 512);                        // 12.8 MB
    float* s0   = (float*)(ws + 512 + (size_t)NB * NF * 4);               // 800 KB
    float* S0   = (float*)(ws + 512 + (size_t)NB * NF * 4 + (size_t)NB * NW0 * 4);

    detect_kernel<<<1, 256, 0, stream>>>(faces, flag);

    // fused area + window-prefix: 16 batches x 782 chunks (XCD-swizzled)
    area_prefix_kernel<<<16 * 782, 256, 0, stream>>>(verts, faces, flag, cdf, s0);

    midscan16_kernel<<<NB, 256, 0, stream>>>(s0, S0);

    // fused addoff + normalize: 16 batches x 782 chunks (XCD-swizzled)
    fused_norm_kernel<<<16 * 782, 256, 0, stream>>>(cdf, s0, S0);

    // sample, 2 samples/thread: 16 batches x 128 chunks (XCD-swizzled)
    sample_kernel<<<16 * 128, 256, 0, stream>>>(verts, faces, flag, e1, e2, u, cdf, out);
}

// Round 30
// 162.121 us; speedup vs baseline: 1.2392x; 1.0437x over previous
//
#include <hip/hip_runtime.h>

#pragma clang fp contract(off)

#define NB 16
#define NV 100000
#define NF 200000
#define NP 65536

// XLA ReduceWindowRewriter, base_length = 16:
// 200000 = 12500*16, then 12500 -> 782 -> 49 -> 4 (sequential windows).
#define B16 16
#define NW0 12500
#define NW1 782
#define NW2 49
#define NW3 4

#define TREE_LVL 12              // search levels served from LDS
#define TREE_N   (1 << TREE_LVL) // 4096 slots (index 0 unused)

// XCD-aware swizzle: batches {2x,2x+1} pin to XCD x (blockIdx%8 round-robin).
__device__ __forceinline__ void xcd_map(int p, int& batch, int& chunk) {
    int r = p & 15;
    batch = 2 * (r & 7) + (r >> 3);
    chunk = p >> 4;
}

// faces are int32 (established bit-identically over rounds 1-29).
__device__ __forceinline__ void load_face(const int* __restrict__ faces,
                                          long long fidx,
                                          int& i0, int& i1, int& i2) {
    const int* p = faces + fidx * 3;
    i0 = p[0]; i1 = p[1]; i2 = p[2];
}

// ---------------------------------------------------------------------------
// FUSED area + window-16 prefix (bit-exact): FMA-contracted area into LDS,
// then re-sum window prefix in identical sequential order.
// ---------------------------------------------------------------------------
__global__ void area_prefix_kernel(const float* __restrict__ verts,
                                   const int* __restrict__ faces,
                                   float* __restrict__ cdf,
                                   float* __restrict__ s0) {
    __shared__ float S[256];
    int batch, chunk;
    xcd_map(blockIdx.x, batch, chunk);
    int tid = threadIdx.x;
    int i = chunk * 256 + tid;
    bool valid = (i < NF);
    float a = 0.0f;
    if (valid) {
        size_t gid = (size_t)batch * NF + i;
        const float* vb = verts + (size_t)batch * NV * 3;
        int i0, i1, i2;
        load_face(faces, (long long)gid, i0, i1, i2);
        float ax = vb[3 * i0 + 0], ay = vb[3 * i0 + 1], az = vb[3 * i0 + 2];
        float bx = vb[3 * i1 + 0], by = vb[3 * i1 + 1], bz = vb[3 * i1 + 2];
        float cx = vb[3 * i2 + 0], cy = vb[3 * i2 + 1], cz = vb[3 * i2 + 2];
        float v1x = bx - ax, v1y = by - ay, v1z = bz - az;
        float v2x = cx - ax, v2y = cy - ay, v2z = cz - az;
        float nx = fmaf(v1y, v2z, -(v1z * v2y));
        float ny = fmaf(v1z, v2x, -(v1x * v2z));
        float nz = fmaf(v1x, v2y, -(v1y * v2x));
        float ss = fmaf(nz, nz, fmaf(nx, nx, ny * ny));
        float nrm = sqrtf(ss);
        a = nrm / 2.0f;
    }
    S[tid] = a;
    __syncthreads();
    if (valid) {
        int base = tid & ~15;
        float run = S[base];
        for (int p = base + 1; p <= tid; ++p) run = run + S[p];  // seq order
        cdf[(size_t)batch * NF + i] = run;
        if ((tid & 15) == 15)
            s0[(size_t)batch * NW0 + (i >> 4)] = run;
    }
}

// ---------------------------------------------------------------------------
// Stage B: per batch, scan s0[12500] with the SAME base-16 structure.
// ---------------------------------------------------------------------------
__global__ void midscan16_kernel(const float* __restrict__ s0g, float* __restrict__ S0g) {
    __shared__ float t0[NW0];
    __shared__ float t1[NW1];
    __shared__ float t2[NW2];
    __shared__ float t3[NW3];
    int b = blockIdx.x;
    for (int i = threadIdx.x; i < NW0; i += blockDim.x)
        t0[i] = s0g[(size_t)b * NW0 + i];
    __syncthreads();
    for (int w = threadIdx.x; w < NW1; w += blockDim.x) {
        int st = w * B16, en = st + B16 < NW0 ? st + B16 : NW0;
        float run = 0.0f;
        for (int p = st; p < en; ++p) { run = run + t0[p]; t0[p] = run; }
        t1[w] = run;
    }
    __syncthreads();
    for (int w = threadIdx.x; w < NW2; w += blockDim.x) {
        int st = w * B16, en = st + B16 < NW1 ? st + B16 : NW1;
        float run = 0.0f;
        for (int p = st; p < en; ++p) { run = run + t1[p]; t1[p] = run; }
        t2[w] = run;
    }
    __syncthreads();
    for (int w = threadIdx.x; w < NW3; w += blockDim.x) {
        int st = w * B16, en = st + B16 < NW2 ? st + B16 : NW2;
        float run = 0.0f;
        for (int p = st; p < en; ++p) { run = run + t2[p]; t2[p] = run; }
        t3[w] = run;
    }
    __syncthreads();
    if (threadIdx.x == 0) {
        float run = 0.0f;
        for (int k = 0; k < NW3; ++k) { run = run + t3[k]; t3[k] = run; }
    }
    __syncthreads();
    for (int i = threadIdx.x; i < NW2; i += blockDim.x) {
        int w = i >> 4;
        float off = (w > 0) ? t3[w - 1] : 0.0f;
        t2[i] = off + t2[i];
    }
    __syncthreads();
    for (int i = threadIdx.x; i < NW1; i += blockDim.x) {
        int w = i >> 4;
        float off = (w > 0) ? t2[w - 1] : 0.0f;
        t1[i] = off + t1[i];
    }
    __syncthreads();
    for (int i = threadIdx.x; i < NW0; i += blockDim.x) {
        int w = i >> 4;
        float off = (w > 0) ? t1[w - 1] : 0.0f;
        t0[i] = off + t0[i];
    }
    __syncthreads();
    for (int i = threadIdx.x; i < NW0; i += blockDim.x)
        S0g[(size_t)b * NW0 + i] = t0[i];
}

// ---------------------------------------------------------------------------
// FUSED addoff + normalize (bit-exact): total = S0[NW0-2] + s0[NW0-1];
// rcp = 1/total; cdf[i] = (off + cdf[i]) * rcp.
// ---------------------------------------------------------------------------
__global__ void fused_norm_kernel(float* __restrict__ cdf,
                                  const float* __restrict__ s0,
                                  const float* __restrict__ S0) {
    int batch, chunk;
    xcd_map(blockIdx.x, batch, chunk);
    int i = chunk * 256 + threadIdx.x;
    if (i >= NF) return;
    const float* S0b = S0 + (size_t)batch * NW0;
    float total = S0b[NW0 - 2] + s0[(size_t)batch * NW0 + NW0 - 1];
    float rcp = 1.0f / total;
    int j = i >> 4;
    float off = (j > 0) ? S0b[j - 1] : 0.0f;
    float* p = cdf + (size_t)batch * NF + i;
    *p = (off + *p) * rcp;
}

// ---------------------------------------------------------------------------
// Tree build — ONCE per batch (16 blocks): heap node n (1..4095), level
// k = 31-clz(n), replay path bits to get its (low,high); Tg[b][n] = c[mid].
// ---------------------------------------------------------------------------
__global__ void treebuild_kernel(const float* __restrict__ cdf, float* __restrict__ Tg) {
    int b = blockIdx.x;
    const float* c = cdf + (size_t)b * NF;
    float* T = Tg + (size_t)b * TREE_N;
    for (int n = 1 + threadIdx.x; n < TREE_N; n += blockDim.x) {
        int k = 31 - __clz(n);
        int low = 0, high = NF;
        for (int j = k - 1; j >= 0; --j) {
            int mid = (low + high) >> 1;
            if ((n >> j) & 1) low = mid; else high = mid;
        }
        T[n] = c[(low + high) >> 1];
    }
}

// ---------------------------------------------------------------------------
// Sample: stage the per-batch heap into LDS (coalesced), 12 LDS levels +
// 6 global levels (identical comparisons -> bit-exact), f64 epilogue.
// ---------------------------------------------------------------------------
__global__ void sample_kernel(const float* __restrict__ verts,
                              const int* __restrict__ faces,
                              const float* __restrict__ e1,
                              const float* __restrict__ e2,
                              const float* __restrict__ u,
                              const float* __restrict__ cdf,
                              const float* __restrict__ Tg,
                              float* __restrict__ out) {
    __shared__ float T[TREE_N];
    int batch, chunk;
    xcd_map(blockIdx.x, batch, chunk);
    int b = batch;
    const float* c = cdf + (size_t)b * NF;
    const float* Tb = Tg + (size_t)b * TREE_N;

    for (int n = threadIdx.x; n < TREE_N; n += blockDim.x)   // coalesced stage
        T[n] = Tb[n];
    __syncthreads();

    int li = chunk * 256 + threadIdx.x;      // sample index in [0, NP)
    int gid = (b << 16) + li;                // P = 65536

    float uv = u[gid];
    int low = 0, high = NF, node = 1;
    #pragma unroll
    for (int it = 0; it < TREE_LVL; ++it) {  // LDS levels (separate pipe)
        int mid = (low + high) >> 1;
        bool gl = (uv <= T[node]);
        node = 2 * node + (gl ? 0 : 1);
        if (gl) high = mid; else low = mid;
    }
    #pragma unroll
    for (int it = TREE_LVL; it < 18; ++it) { // deep global levels
        int mid = (low + high) >> 1;
        bool gl = (uv <= c[mid]);
        if (gl) high = mid; else low = mid;
    }
    int idx = high < NF - 1 ? high : NF - 1;

    const float* vb = verts + (size_t)b * NV * 3;
    int i0, i1, i2;
    load_face(faces, (long long)b * NF + idx, i0, i1, i2);
    double ax = vb[3 * i0 + 0], ay = vb[3 * i0 + 1], az = vb[3 * i0 + 2];
    double bx = vb[3 * i1 + 0], by = vb[3 * i1 + 1], bz = vb[3 * i1 + 2];
    double cx = vb[3 * i2 + 0], cy = vb[3 * i2 + 1], cz = vb[3 * i2 + 2];

    double v1x = bx - ax, v1y = by - ay, v1z = bz - az;
    double v2x = cx - ax, v2y = cy - ay, v2z = cz - az;
    double nx = v1y * v2z - v1z * v2y;
    double ny = v1z * v2x - v1x * v2z;
    double nz = v1x * v2y - v1y * v2x;
    double ss = (nx * nx + ny * ny) + nz * nz;
    double nrm = sqrt(ss);
    double unx = nx / nrm, uny = ny / nrm, unz = nz / nrm;

    double s = sqrt((double)e1[gid]);
    double t = (double)e2[gid];
    double w0 = 1.0 - s;
    double w1 = (1.0 - t) * s;
    double w2 = t * s;
    double px = (ax * w0 + bx * w1) + cx * w2;
    double py = (ay * w0 + by * w1) + cy * w2;
    double pz = (az * w0 + bz * w1) + cz * w2;

    size_t po = (size_t)gid * 3;
    out[po + 0] = (float)px;
    out[po + 1] = (float)py;
    out[po + 2] = (float)pz;
    size_t no = (size_t)NB * NP * 3 + po;
    out[no + 0] = (float)unx;
    out[no + 1] = (float)uny;
    out[no + 2] = (float)unz;
}

extern "C" void kernel_launch(void* const* d_in, const int* in_sizes, int n_in,
                              void* d_out, int out_size, void* d_ws, size_t ws_size,
                              hipStream_t stream) {
    const float* verts = (const float*)d_in[0];  // fp32
    const int*   faces = (const int*)d_in[1];    // int32
    const float* e1    = (const float*)d_in[2];
    const float* e2    = (const float*)d_in[3];
    const float* u     = (const float*)d_in[4];
    float* out = (float*)d_out;

    char* ws = (char*)d_ws;
    float* cdf = (float*)(ws + 512);                         // 12.8 MB
    float* s0  = (float*)(ws + 512 + (size_t)NB * NF * 4);                // 800 KB
    float* S0  = (float*)(ws + 512 + (size_t)NB * NF * 4 + (size_t)NB * NW0 * 4);
    float* Tg  = (float*)(ws + 512 + (size_t)NB * NF * 4 + 2 * (size_t)NB * NW0 * 4);

    // fused area + window-prefix: 16 batches x 782 chunks (XCD-swizzled)
    area_prefix_kernel<<<16 * 782, 256, 0, stream>>>(verts, faces, cdf, s0);

    midscan16_kernel<<<NB, 256, 0, stream>>>(s0, S0);

    // fused addoff + normalize: 16 batches x 782 chunks (XCD-swizzled)
    fused_norm_kernel<<<16 * 782, 256, 0, stream>>>(cdf, s0, S0);

    // per-batch heap build (tiny)
    treebuild_kernel<<<NB, 256, 0, stream>>>(cdf, Tg);

    // sample with staged LDS tree: 16 batches x 256 chunks (XCD-swizzled)
    sample_kernel<<<16 * 256, 256, 0, stream>>>(verts, faces, e1, e2, u, cdf, Tg, out);
}